// Round 2
// baseline (37852.530 us; speedup 1.0000x reference)
//
#include <hip/hip_runtime.h>
#include <math.h>

#define GRV 9.80665f

__device__ __forceinline__ void mat3mul(const float* A, const float* B, float* C){
  #pragma unroll
  for (int r=0;r<3;r++)
    #pragma unroll
    for (int c=0;c<3;c++)
      C[r*3+c] = A[r*3]*B[c] + A[r*3+1]*B[3+c] + A[r*3+2]*B[6+c];
}

// skew(a)[r][c]
__device__ __forceinline__ float skew_el(const float* a, int r, int c){
  if (r==0) return (c==1)? -a[2] : ((c==2)? a[1] : 0.f);
  if (r==1) return (c==0)?  a[2] : ((c==2)? -a[0] : 0.f);
  return (c==0)? -a[1] : ((c==1)? a[0] : 0.f);
}

// c1 = sin(a)/a, c2 = (1-cos a)/a^2, c3 = (a - sin a)/a^3 — poly for small a (rel err <1e-9 for a<0.05)
__device__ __forceinline__ void so3coeffs(float a2, float* c1, float* c2, float* c3){
  if (a2 < 2.5e-3f){
    float a4 = a2*a2;
    *c1 = 1.f      - a2*(1.f/6.f)   + a4*(1.f/120.f);
    *c2 = 0.5f     - a2*(1.f/24.f)  + a4*(1.f/720.f);
    *c3 = (1.f/6.f)- a2*(1.f/120.f) + a4*(1.f/5040.f);
  } else {
    float a = sqrtf(a2);
    float sa = sinf(a), ca = cosf(a);
    *c1 = sa/a;
    *c2 = (1.f-ca)/a2;
    *c3 = (a-sa)/(a2*a);
  }
}

__device__ __forceinline__ void so3exp_fast(const float* phi, float* R){
  float p0=phi[0], p1=phi[1], p2=phi[2];
  float a2 = p0*p0+p1*p1+p2*p2;
  float c1,c2,c3; so3coeffs(a2,&c1,&c2,&c3);
  R[0]=1.f+c2*(p0*p0-a2); R[4]=1.f+c2*(p1*p1-a2); R[8]=1.f+c2*(p2*p2-a2);
  R[1]=-c1*p2+c2*p0*p1;   R[3]= c1*p2+c2*p0*p1;
  R[2]= c1*p1+c2*p0*p2;   R[6]=-c1*p1+c2*p0*p2;
  R[5]=-c1*p0+c2*p1*p2;   R[7]= c1*p0+c2*p1*p2;
}

// helpers over shared state st[]: R=st[0..8], v=st[9..11], p=st[12..14]
#define VSR(r,c) ((r)==0 ? (st[10]*st[6+(c)] - st[11]*st[3+(c)]) : \
                  (r)==1 ? (st[11]*st[(c)]   - st[ 9]*st[6+(c)]) : \
                           (st[ 9]*st[3+(c)] - st[10]*st[(c)]))
#define PSR(r,c) ((r)==0 ? (st[13]*st[6+(c)] - st[14]*st[3+(c)]) : \
                  (r)==1 ? (st[14]*st[(c)]   - st[12]*st[6+(c)]) : \
                           (st[12]*st[3+(c)] - st[13]*st[(c)]))
#define SGR(r,c) ((r)==0 ? (GRV*st[3+(c)]) : (r)==1 ? (-GRV*st[(c)]) : 0.f)
// N(1,3)[r][c] and N(2,3)[r][c]
#define N13(r,c) (-dtv*VSR(r,c) - 0.5f*dt2*SGR(r,c))
#define N23(r,c) (-dtv*PSR(r,c) - 0.5f*dt2*VSR(r,c) - (dt2*dtv*(1.f/6.f))*SGR(r,c))

__global__ __launch_bounds__(512)
void iekf_kernel(const float* __restrict__ t, const float* __restrict__ u,
                 const float* __restrict__ mcov, const float* __restrict__ vmes,
                 const float* __restrict__ ang0, const float* __restrict__ winit,
                 float* __restrict__ out, int N)
{
  const int tid = threadIdx.x;

  __shared__ float Ps[21][22];   // final P per step
  __shared__ float As[21][22];   // A = sym(P) + GQG^T
  __shared__ float Bs[9][22];    // rows 0..8 of Phi@A
  __shared__ float Cs[21][10];   // cols 0..8 of Phi@A@Phi^T
  __shared__ float st[33];       // Rot 0-8, v 9-11, p 12-14, bo 15-17, ba 18-20, Rci 21-29, tci 30-32
  __shared__ float Hm[2][21];
  __shared__ float H2s[2][22];   // H @ Phi
  __shared__ float PHts[21][2];
  __shared__ float Km[21][2];
  __shared__ float dxs[21];
  __shared__ float Sv[3];
  __shared__ float rsh[2];

  const int i  = tid/21, j  = tid - i*21;     // tid<441 (phase A/H); tid<189 (phase B: i in 0..8)
  const int bi = i/3,  ri = i - bi*3;
  const int bj = j/3,  rj = j - bj*3;
  const int ci9 = tid/9, cj9 = tid - ci9*9;   // tid<189 (phase C: ci9 0..20, cj9 0..8)

  // carry registers (meaningful only in thread 448)
  float Rr[9]={0}, vr[3]={0}, pr[3]={0}, bor[3]={0}, bar[3]={0}, Rcir[9]={0}, tcir[3]={0};

  // ---------------- init ----------------
  if (tid < 441) Ps[i][j] = 0.f;
  __syncthreads();
  if (tid == 448){
    float beta[6];
    #pragma unroll
    for (int k=0;k<6;k++) beta[k] = powf(10.f, tanhf(winit[k]));
    Ps[0][0]=0.001f*beta[0]; Ps[1][1]=0.001f*beta[0];
    Ps[3][3]=0.1f*beta[1];   Ps[4][4]=0.1f*beta[1];
    for (int c=9;c<12;c++)  Ps[c][c]=0.1f*beta[2];
    for (int c=12;c<15;c++) Ps[c][c]=0.1f*beta[3];
    for (int c=15;c<18;c++) Ps[c][c]=1e-6f*beta[4];
    for (int c=18;c<21;c++) Ps[c][c]=1e-5f*beta[5];
    float cr=cosf(ang0[0]), sr=sinf(ang0[0]);
    float cp=cosf(ang0[1]), sp=sinf(ang0[1]);
    float cy=cosf(ang0[2]), sy=sinf(ang0[2]);
    float Rz[9]={cy,-sy,0.f, sy,cy,0.f, 0.f,0.f,1.f};
    float Ry[9]={cp,0.f,sp, 0.f,1.f,0.f, -sp,0.f,cp};
    float Rx[9]={1.f,0.f,0.f, 0.f,cr,-sr, 0.f,sr,cr};
    float T1[9]; mat3mul(Rz,Ry,T1); mat3mul(T1,Rx,Rr);
    vr[0]=vmes[0]; vr[1]=vmes[1]; vr[2]=vmes[2];
    #pragma unroll
    for (int k=0;k<9;k++) Rcir[k] = (k%4==0)?1.f:0.f;
    #pragma unroll
    for (int k=0;k<9;k++){ st[k]=Rr[k]; st[21+k]=Rcir[k]; }
    #pragma unroll
    for (int k=0;k<3;k++){ st[9+k]=vr[k]; st[12+k]=0.f; st[15+k]=0.f; st[18+k]=0.f; st[30+k]=0.f; }
  }
  __syncthreads();

  // prefetch for n=1
  float t_nm1 = t[0];
  float t_n   = (N>1)? t[1] : t[0];
  float mc0   = (N>1)? mcov[2] : 0.f;
  float mc1   = (N>1)? mcov[3] : 0.f;
  float u6[6] = {0,0,0,0,0,0};
  if (tid==448 && N>1){
    #pragma unroll
    for (int k=0;k<6;k++) u6[k]=u[6+k];
  }

  for (int n=1; n<N; n++){
    const float dtv = t_n - t_nm1;
    const float dt2 = dtv*dtv;
    float Rnp[9], vnp[3], pnp[3];   // predicted state (thread 448 only)
    #pragma unroll
    for (int k=0;k<9;k++) Rnp[k]=0.f;
    vnp[0]=vnp[1]=vnp[2]=0.f; pnp[0]=pnp[1]=pnp[2]=0.f;

    // ===== phase A: A = sym(P) + GQG^T (sparse) | scalar propagate + H,r | stream out =====
    if (tid < 441){
      float s = 0.5f*(Ps[i][j]+Ps[j][i]);
      if (bi<3 && bj<3){
        float wi0,wi1,wi2, wj0,wj1,wj2;
        if (bi==0){ wi0=st[ri*3]; wi1=st[ri*3+1]; wi2=st[ri*3+2]; }
        else if (bi==1){ wi0=VSR(ri,0); wi1=VSR(ri,1); wi2=VSR(ri,2); }
        else { wi0=PSR(ri,0); wi1=PSR(ri,1); wi2=PSR(ri,2); }
        if (bj==0){ wj0=st[rj*3]; wj1=st[rj*3+1]; wj2=st[rj*3+2]; }
        else if (bj==1){ wj0=VSR(rj,0); wj1=VSR(rj,1); wj2=VSR(rj,2); }
        else { wj0=PSR(rj,0); wj1=PSR(rj,1); wj2=PSR(rj,2); }
        s += 1e-3f*dt2*(wi0*wj0+wi1*wj1+wi2*wj2);
        if (bi==1 && bj==1)
          s += 1e-2f*dt2*(st[ri*3]*st[rj*3]+st[ri*3+1]*st[rj*3+1]+st[ri*3+2]*st[rj*3+2]);
      } else if (i==j){
        float q = (i<12)? 6e-9f : ((i<15)? 2e-4f : 1e-9f);
        s += q*dt2;
      }
      As[i][j] = s;
    } else if (tid == 448){
      // propagate
      float ub0=u6[3]-bar[0], ub1=u6[4]-bar[1], ub2=u6[5]-bar[2];
      float ac0=Rr[0]*ub0+Rr[1]*ub1+Rr[2]*ub2;
      float ac1=Rr[3]*ub0+Rr[4]*ub1+Rr[5]*ub2;
      float ac2=Rr[6]*ub0+Rr[7]*ub1+Rr[8]*ub2 - GRV;
      vnp[0]=vr[0]+ac0*dtv; vnp[1]=vr[1]+ac1*dtv; vnp[2]=vr[2]+ac2*dtv;
      pnp[0]=pr[0]+vr[0]*dtv+0.5f*ac0*dt2;
      pnp[1]=pr[1]+vr[1]*dtv+0.5f*ac1*dt2;
      pnp[2]=pr[2]+vr[2]*dtv+0.5f*ac2*dt2;
      float om[3] = {(u6[0]-bor[0])*dtv, (u6[1]-bor[1])*dtv, (u6[2]-bor[2])*dtv};
      float E[9]; so3exp_fast(om, E);
      mat3mul(Rr, E, Rnp);
      // H and r
      float Rb[9]; mat3mul(Rnp, Rcir, Rb);
      float vi[3];
      #pragma unroll
      for (int r=0;r<3;r++) vi[r] = Rnp[r]*vnp[0] + Rnp[3+r]*vnp[1] + Rnp[6+r]*vnp[2];
      float omm[3] = {u6[0]-bor[0], u6[1]-bor[1], u6[2]-bor[2]};
      float vb[3];
      #pragma unroll
      for (int r=0;r<3;r++){
        float sk = skew_el(tcir,r,0)*omm[0] + skew_el(tcir,r,1)*omm[1] + skew_el(tcir,r,2)*omm[2];
        vb[r] = Rcir[r]*vi[0] + Rcir[3+r]*vi[1] + Rcir[6+r]*vi[2] + sk;
      }
      #pragma unroll
      for (int a=0;a<2;a++){
        int sr2 = 1+a;
        #pragma unroll
        for (int c=0;c<3;c++){
          Hm[a][c]    = 0.f;
          Hm[a][6+c]  = 0.f;
          Hm[a][12+c] = 0.f;
          Hm[a][3+c]  = Rb[c*3+sr2];
          Hm[a][9+c]  = skew_el(tcir, sr2, c);
          float hv = Rcir[sr2]*skew_el(vi,0,c) + Rcir[3+sr2]*skew_el(vi,1,c) + Rcir[6+sr2]*skew_el(vi,2,c);
          Hm[a][15+c] = hv;
          Hm[a][18+c] = -skew_el(omm, sr2, c);
        }
        rsh[a] = -vb[sr2];
      }
    } else if (tid >= 449 && tid < 482){
      out[(size_t)(n-1)*33 + (tid-449)] = st[tid-449];
    }
    __syncthreads(); // 1

    // ===== phase B: Bs(rows 0..8) = (A + N@A) | H2 = H + H@N =====
    if (tid < 189){
      float s = As[i][j];
      if (i < 3){
        s -= dtv*(st[ri*3]*As[9][j] + st[ri*3+1]*As[10][j] + st[ri*3+2]*As[11][j]);
      } else if (i < 6){
        if (ri==0)      s += GRV*dtv*As[1][j];
        else if (ri==1) s -= GRV*dtv*As[0][j];
        s += N13(ri,0)*As[9][j] + N13(ri,1)*As[10][j] + N13(ri,2)*As[11][j];
        s -= dtv*(st[ri*3]*As[12][j] + st[ri*3+1]*As[13][j] + st[ri*3+2]*As[14][j]);
      } else {
        if (ri==0)      s += GRV*0.5f*dt2*As[1][j];
        else if (ri==1) s -= GRV*0.5f*dt2*As[0][j];
        s += dtv*As[3+ri][j];
        s += N23(ri,0)*As[9][j] + N23(ri,1)*As[10][j] + N23(ri,2)*As[11][j];
        s -= 0.5f*dt2*(st[ri*3]*As[12][j] + st[ri*3+1]*As[13][j] + st[ri*3+2]*As[14][j]);
      }
      Bs[i][j] = s;
    } else if (tid >= 448 && tid < 490){
      int lane = tid-448; int c = lane/21, jj = lane - c*21;
      float h = Hm[c][jj];
      if (jj==0)      h -= GRV*dtv*Hm[c][4];
      else if (jj==1) h += GRV*dtv*Hm[c][3];
      else if (jj>=9 && jj<12){
        int jc=jj-9;
        h += Hm[c][3]*N13(0,jc) + Hm[c][4]*N13(1,jc) + Hm[c][5]*N13(2,jc);
      } else if (jj>=12 && jj<15){
        int jc=jj-12;
        h -= dtv*(Hm[c][3]*st[jc] + Hm[c][4]*st[3+jc] + Hm[c][5]*st[6+jc]);
      }
      H2s[c][jj] = h;
    }
    __syncthreads(); // 2

    // ===== phase C: Cs(cols 0..8) = B + B@N^T | PHt = B @ H2^T =====
    if (tid < 189){
      const int ii = ci9, jj = cj9, r = jj - (jj/3)*3;
      #define BRD(k) ((ii<9)? Bs[ii][k] : As[ii][k])
      float s = BRD(jj);
      if (jj < 3){
        s -= dtv*(st[r*3]*BRD(9) + st[r*3+1]*BRD(10) + st[r*3+2]*BRD(11));
      } else if (jj < 6){
        if (r==0)      s += GRV*dtv*BRD(1);
        else if (r==1) s -= GRV*dtv*BRD(0);
        s += N13(r,0)*BRD(9) + N13(r,1)*BRD(10) + N13(r,2)*BRD(11);
        s -= dtv*(st[r*3]*BRD(12) + st[r*3+1]*BRD(13) + st[r*3+2]*BRD(14));
      } else {
        if (r==0)      s += GRV*0.5f*dt2*BRD(1);
        else if (r==1) s -= GRV*0.5f*dt2*BRD(0);
        s += dtv*BRD(3+r);
        s += N23(r,0)*BRD(9) + N23(r,1)*BRD(10) + N23(r,2)*BRD(11);
        s -= 0.5f*dt2*(st[r*3]*BRD(12) + st[r*3+1]*BRD(13) + st[r*3+2]*BRD(14));
      }
      Cs[ii][jj] = s;
      #undef BRD
    } else if (tid >= 448 && tid < 490){
      int lane = tid-448, ii = lane>>1, cc = lane&1;
      float a = 0.f;
      #pragma unroll
      for (int k=0;k<21;k++) a += ((ii<9)? Bs[ii][k] : As[ii][k]) * H2s[cc][k];
      PHts[ii][cc] = a;
    }
    __syncthreads(); // 3

    // ===== phase G: S, K, dx =====
    if (tid < 21){
      float s00=mc0, s01=0.f, s10=0.f, s11=mc1;
      #pragma unroll
      for (int k=0;k<21;k++){
        s00 += Hm[0][k]*PHts[k][0];
        s01 += Hm[0][k]*PHts[k][1];
        s10 += Hm[1][k]*PHts[k][0];
        s11 += Hm[1][k]*PHts[k][1];
      }
      float det = s00*s11 - s01*s10;
      float id  = 1.f/det;
      float i00 =  s11*id, i01 = -s01*id, i10 = -s10*id, i11 = s00*id;
      float p0 = PHts[tid][0], p1 = PHts[tid][1];
      float k0 = p0*i00 + p1*i10;
      float k1 = p0*i01 + p1*i11;
      Km[tid][0]=k0; Km[tid][1]=k1;
      dxs[tid] = k0*rsh[0] + k1*rsh[1];
      if (tid==0){ Sv[0]=s00; Sv[1]=0.5f*(s01+s10); Sv[2]=s11; }
    }
    __syncthreads(); // 4

    // ===== phase H: P = Pprop - K(PHt)^T - (PHt)K^T + K S K^T | scalar retraction =====
    if (tid < 441){
      float base = (j<9)? Cs[i][j] : ((i<9)? Bs[i][j] : As[i][j]);
      float ki0=Km[i][0], ki1=Km[i][1];
      float kj0=Km[j][0], kj1=Km[j][1];
      float pi0=PHts[i][0], pi1=PHts[i][1];
      float pj0=PHts[j][0], pj1=PHts[j][1];
      float tsum = (ki0*pj0 + ki1*pj1) + (pi0*kj0 + pi1*kj1);
      float quad = Sv[0]*(ki0*kj0) + Sv[1]*(ki0*kj1 + ki1*kj0) + Sv[2]*(ki1*kj1);
      Ps[i][j] = base - tsum + quad;
    } else if (tid == 448){
      float dxl[21];
      #pragma unroll
      for (int k=0;k<21;k++) dxl[k]=dxs[k];
      float p0=dxl[0], p1=dxl[1], p2=dxl[2];
      float a2 = p0*p0+p1*p1+p2*p2;
      float c1,c2,c3; so3coeffs(a2,&c1,&c2,&c3);
      float dR[9], Jm[9];
      dR[0]=1.f+c2*(p0*p0-a2); dR[4]=1.f+c2*(p1*p1-a2); dR[8]=1.f+c2*(p2*p2-a2);
      dR[1]=-c1*p2+c2*p0*p1;   dR[3]= c1*p2+c2*p0*p1;
      dR[2]= c1*p1+c2*p0*p2;   dR[6]=-c1*p1+c2*p0*p2;
      dR[5]=-c1*p0+c2*p1*p2;   dR[7]= c1*p0+c2*p1*p2;
      Jm[0]=1.f+c3*(p0*p0-a2); Jm[4]=1.f+c3*(p1*p1-a2); Jm[8]=1.f+c3*(p2*p2-a2);
      Jm[1]=-c2*p2+c3*p0*p1;   Jm[3]= c2*p2+c3*p0*p1;
      Jm[2]= c2*p1+c3*p0*p2;   Jm[6]=-c2*p1+c3*p0*p2;
      Jm[5]=-c2*p0+c3*p1*p2;   Jm[7]= c2*p0+c3*p1*p2;
      float xv[3], xp[3];
      #pragma unroll
      for (int r=0;r<3;r++){
        xv[r]=Jm[r*3]*dxl[3]+Jm[r*3+1]*dxl[4]+Jm[r*3+2]*dxl[5];
        xp[r]=Jm[r*3]*dxl[6]+Jm[r*3+1]*dxl[7]+Jm[r*3+2]*dxl[8];
      }
      float Rn2[9]; mat3mul(dR, Rnp, Rn2);
      float vn2[3], pn2[3];
      #pragma unroll
      for (int r=0;r<3;r++){
        vn2[r]=dR[r*3]*vnp[0]+dR[r*3+1]*vnp[1]+dR[r*3+2]*vnp[2] + xv[r];
        pn2[r]=dR[r*3]*pnp[0]+dR[r*3+1]*pnp[1]+dR[r*3+2]*pnp[2] + xp[r];
      }
      #pragma unroll
      for (int r=0;r<3;r++){ bor[r]+=dxl[9+r]; bar[r]+=dxl[12+r]; }
      float E2[9]; so3exp_fast(dxl+15, E2);
      float Rc2[9]; mat3mul(E2, Rcir, Rc2);
      #pragma unroll
      for (int k=0;k<9;k++) Rcir[k]=Rc2[k];
      #pragma unroll
      for (int r=0;r<3;r++) tcir[r]+=dxl[18+r];
      #pragma unroll
      for (int k=0;k<9;k++) Rr[k]=Rn2[k];
      #pragma unroll
      for (int r=0;r<3;r++){ vr[r]=vn2[r]; pr[r]=pn2[r]; }
      #pragma unroll
      for (int k=0;k<9;k++){ st[k]=Rr[k]; st[21+k]=Rcir[k]; }
      #pragma unroll
      for (int r=0;r<3;r++){ st[9+r]=vr[r]; st[12+r]=pr[r]; st[15+r]=bor[r]; st[18+r]=bar[r]; st[30+r]=tcir[r]; }
    }
    // prefetch next step's inputs
    {
      int np = n+1;
      t_nm1 = t_n;
      if (np < N){
        t_n = t[np];
        mc0 = mcov[np*2]; mc1 = mcov[np*2+1];
        if (tid==448){
          #pragma unroll
          for (int k=0;k<6;k++) u6[k]=u[np*6+k];
        }
      }
    }
    __syncthreads(); // 5
  }

  // final output row
  if (tid >= 449 && tid < 482){
    out[(size_t)(N-1)*33 + (tid-449)] = st[tid-449];
  }
}

extern "C" void kernel_launch(void* const* d_in, const int* in_sizes, int n_in,
                              void* d_out, int out_size, void* d_ws, size_t ws_size,
                              hipStream_t stream) {
  const float* t     = (const float*)d_in[0];
  const float* u     = (const float*)d_in[1];
  const float* mcov  = (const float*)d_in[2];
  const float* vmes  = (const float*)d_in[3];
  // d_in[4] = p_mes (unused by reference)
  const float* ang0  = (const float*)d_in[5];
  const float* winit = (const float*)d_in[6];
  float* out = (float*)d_out;
  int N = in_sizes[0];
  iekf_kernel<<<dim3(1), dim3(512), 0, stream>>>(t, u, mcov, vmes, ang0, winit, out, N);
}

// Round 3
// 15283.501 us; speedup vs baseline: 2.4767x; 2.4767x over previous
//
#include <hip/hip_runtime.h>
#include <math.h>

#define GRV 9.80665f

__device__ __forceinline__ void so3coeffs(float a2, float* c1, float* c2, float* c3){
  if (a2 < 2.5e-3f){
    float a4 = a2*a2;
    *c1 = 1.f      - a2*(1.f/6.f)   + a4*(1.f/120.f);
    *c2 = 0.5f     - a2*(1.f/24.f)  + a4*(1.f/720.f);
    *c3 = (1.f/6.f)- a2*(1.f/120.f) + a4*(1.f/5040.f);
  } else {
    float a = sqrtf(a2);
    float sa = sinf(a), ca = cosf(a);
    *c1 = sa/a; *c2 = (1.f-ca)/a2; *c3 = (a-sa)/(a2*a);
  }
}

// R = so3exp([p0,p1,p2]) ; J coefficients via c2/c3 if needed by caller
__device__ __forceinline__ void so3exp_u(float p0, float p1, float p2, float* R){
  float a2 = p0*p0+p1*p1+p2*p2;
  float c1,c2,c3; so3coeffs(a2,&c1,&c2,&c3);
  R[0]=1.f+c2*(p0*p0-a2); R[4]=1.f+c2*(p1*p1-a2); R[8]=1.f+c2*(p2*p2-a2);
  R[1]=-c1*p2+c2*p0*p1;   R[3]= c1*p2+c2*p0*p1;
  R[2]= c1*p1+c2*p0*p2;   R[6]=-c1*p1+c2*p0*p2;
  R[5]=-c1*p0+c2*p1*p2;   R[7]= c1*p0+c2*p1*p2;
}

__device__ __forceinline__ void mat3mul_u(const float* A, const float* B, float* C){
  #pragma unroll
  for (int r=0;r<3;r++)
    #pragma unroll
    for (int c=0;c<3;c++)
      C[r*3+c] = A[r*3]*B[c] + A[r*3+1]*B[3+c] + A[r*3+2]*B[6+c];
}

// X := X + X @ N^T  acting on one register-resident row (21 floats).
__device__ __forceinline__ void col_update(float* a, const float* R_, const float* n13,
                                           const float* n23, float dtv, float hdt2,
                                           float Gdt, float Ghdt2){
  float nb[9];
  #pragma unroll
  for (int jb=0;jb<3;jb++)
    nb[jb] = a[jb] - dtv*(R_[jb*3]*a[9]+R_[jb*3+1]*a[10]+R_[jb*3+2]*a[11]);
  #pragma unroll
  for (int r=0;r<3;r++){
    float s = a[3+r];
    if (r==0) s += Gdt*a[1];
    if (r==1) s -= Gdt*a[0];
    s += n13[r*3]*a[9]+n13[r*3+1]*a[10]+n13[r*3+2]*a[11];
    s -= dtv*(R_[r*3]*a[12]+R_[r*3+1]*a[13]+R_[r*3+2]*a[14]);
    nb[3+r]=s;
  }
  #pragma unroll
  for (int r=0;r<3;r++){
    float s = a[6+r];
    if (r==0) s += Ghdt2*a[1];
    if (r==1) s -= Ghdt2*a[0];
    s += dtv*a[3+r];
    s += n23[r*3]*a[9]+n23[r*3+1]*a[10]+n23[r*3+2]*a[11];
    s -= hdt2*(R_[r*3]*a[12]+R_[r*3+1]*a[13]+R_[r*3+2]*a[14]);
    nb[6+r]=s;
  }
  #pragma unroll
  for (int k=0;k<9;k++) a[k]=nb[k];
}

#define SEL9(e0,e1,e2,e3,e4,e5,e6,e7,e8) \
  (lane==0?(e0):lane==1?(e1):lane==2?(e2):lane==3?(e3):lane==4?(e4):lane==5?(e5):lane==6?(e6):lane==7?(e7):(e8))

__global__ __launch_bounds__(64)
void iekf_kernel(const float* __restrict__ t, const float* __restrict__ u,
                 const float* __restrict__ mcov, const float* __restrict__ vmes,
                 const float* __restrict__ ang0, const float* __restrict__ winit,
                 float* __restrict__ out, int N)
{
  const int lane = threadIdx.x;

  __shared__ float TP1[21*24];
  __shared__ float TP2[21*24];
  __shared__ float PH[44];
  __shared__ float stG[36];

  // uniform state (identical in every lane)
  float R_[9], v_[3], p_[3], bo_[3], ba_[3], Rci_[9], tci_[3];
  float creg[21];   // lane's row of P (lanes 0..20)

  // ---------------- init (uniform) ----------------
  float beta[6];
  #pragma unroll
  for (int k=0;k<6;k++) beta[k] = powf(10.f, tanhf(winit[k]));
  {
    float cr=cosf(ang0[0]), sr=sinf(ang0[0]);
    float cp=cosf(ang0[1]), sp=sinf(ang0[1]);
    float cy=cosf(ang0[2]), sy=sinf(ang0[2]);
    float Rz[9]={cy,-sy,0.f, sy,cy,0.f, 0.f,0.f,1.f};
    float Ry[9]={cp,0.f,sp, 0.f,1.f,0.f, -sp,0.f,cp};
    float Rx[9]={1.f,0.f,0.f, 0.f,cr,-sr, 0.f,sr,cr};
    float T1m[9]; mat3mul_u(Rz,Ry,T1m); mat3mul_u(T1m,Rx,R_);
  }
  v_[0]=vmes[0]; v_[1]=vmes[1]; v_[2]=vmes[2];
  #pragma unroll
  for (int k=0;k<3;k++){ p_[k]=0.f; bo_[k]=0.f; ba_[k]=0.f; tci_[k]=0.f; }
  #pragma unroll
  for (int k=0;k<9;k++) Rci_[k] = (k%4==0)?1.f:0.f;

  {
    float dl = (lane==0||lane==1)? 1e-3f*beta[0]
             : (lane==3||lane==4)? 0.1f*beta[1]
             : (lane>=9&&lane<12)? 0.1f*beta[2]
             : (lane>=12&&lane<15)? 0.1f*beta[3]
             : (lane>=15&&lane<18)? 1e-6f*beta[4]
             : (lane>=18&&lane<21)? 1e-5f*beta[5] : 0.f;
    #pragma unroll
    for (int j=0;j<21;j++) creg[j] = (j==lane)? dl : 0.f;
  }

  if (lane==0){
    ((float4*)stG)[0] = make_float4(R_[0],R_[1],R_[2],R_[3]);
    ((float4*)stG)[1] = make_float4(R_[4],R_[5],R_[6],R_[7]);
    ((float4*)stG)[2] = make_float4(R_[8],v_[0],v_[1],v_[2]);
    ((float4*)stG)[3] = make_float4(p_[0],p_[1],p_[2],bo_[0]);
    ((float4*)stG)[4] = make_float4(bo_[1],bo_[2],ba_[0],ba_[1]);
    ((float4*)stG)[5] = make_float4(ba_[2],Rci_[0],Rci_[1],Rci_[2]);
    ((float4*)stG)[6] = make_float4(Rci_[3],Rci_[4],Rci_[5],Rci_[6]);
    ((float4*)stG)[7] = make_float4(Rci_[7],Rci_[8],tci_[0],tci_[1]);
    ((float4*)stG)[8] = make_float4(tci_[2],0.f,0.f,0.f);
  }

  // prefetch for n=1 (uniform)
  float t_nm1 = t[0];
  float t_n   = (N>1)? t[1] : t[0];
  float mc0   = (N>1)? mcov[2] : 0.f;
  float mc1   = (N>1)? mcov[3] : 0.f;
  float u6[6] = {0,0,0,0,0,0};
  if (N>1){
    #pragma unroll
    for (int k=0;k<6;k++) u6[k]=u[6+k];
  }

  for (int n=1; n<N; n++){
    const float dtv = t_n - t_nm1;
    const float dt2 = dtv*dtv;
    const float hdt2 = 0.5f*dt2;
    const float sdt3 = dt2*dtv*(1.f/6.f);
    const float Gdt = GRV*dtv;
    const float Ghdt2 = GRV*hdt2;

    // ---- stream out row n-1 ----
    if (lane<33) out[(size_t)(n-1)*33 + lane] = stG[lane];

    // ---- T1 write: P rows -> TP1 ----
    if (lane<21){
      float4* rp = (float4*)&TP1[lane*24];
      rp[0]=make_float4(creg[0],creg[1],creg[2],creg[3]);
      rp[1]=make_float4(creg[4],creg[5],creg[6],creg[7]);
      rp[2]=make_float4(creg[8],creg[9],creg[10],creg[11]);
      rp[3]=make_float4(creg[12],creg[13],creg[14],creg[15]);
      rp[4]=make_float4(creg[16],creg[17],creg[18],creg[19]);
      TP1[lane*24+20]=creg[20];
    }

    // ---- uniform small algebra: vsr, psr, n13, n23 ----
    float vsr[9], psr[9], n13[9], n23[9];
    #pragma unroll
    for (int c=0;c<3;c++){
      vsr[c]   = v_[1]*R_[6+c] - v_[2]*R_[3+c];
      vsr[3+c] = v_[2]*R_[c]   - v_[0]*R_[6+c];
      vsr[6+c] = v_[0]*R_[3+c] - v_[1]*R_[c];
      psr[c]   = p_[1]*R_[6+c] - p_[2]*R_[3+c];
      psr[3+c] = p_[2]*R_[c]   - p_[0]*R_[6+c];
      psr[6+c] = p_[0]*R_[3+c] - p_[1]*R_[c];
    }
    #pragma unroll
    for (int c=0;c<3;c++){
      float sg0 =  GRV*R_[3+c];
      float sg1 = -GRV*R_[c];
      n13[c]   = -dtv*vsr[c]   - hdt2*sg0;
      n13[3+c] = -dtv*vsr[3+c] - hdt2*sg1;
      n13[6+c] = -dtv*vsr[6+c];
      n23[c]   = -dtv*psr[c]   - hdt2*vsr[c]   - sdt3*sg0;
      n23[3+c] = -dtv*psr[3+c] - hdt2*vsr[3+c] - sdt3*sg1;
      n23[6+c] = -dtv*psr[6+c] - hdt2*vsr[6+c];
    }

    // ---- uniform propagate + H, r ----
    float Rn[9], vnp[3], pnp[3];
    {
      float ub0=u6[3]-ba_[0], ub1=u6[4]-ba_[1], ub2=u6[5]-ba_[2];
      float ac0=R_[0]*ub0+R_[1]*ub1+R_[2]*ub2;
      float ac1=R_[3]*ub0+R_[4]*ub1+R_[5]*ub2;
      float ac2=R_[6]*ub0+R_[7]*ub1+R_[8]*ub2 - GRV;
      vnp[0]=v_[0]+ac0*dtv; vnp[1]=v_[1]+ac1*dtv; vnp[2]=v_[2]+ac2*dtv;
      pnp[0]=p_[0]+v_[0]*dtv+0.5f*ac0*dt2;
      pnp[1]=p_[1]+v_[1]*dtv+0.5f*ac1*dt2;
      pnp[2]=p_[2]+v_[2]*dtv+0.5f*ac2*dt2;
      float E[9]; so3exp_u((u6[0]-bo_[0])*dtv,(u6[1]-bo_[1])*dtv,(u6[2]-bo_[2])*dtv, E);
      mat3mul_u(R_, E, Rn);
    }
    float Hc0[21], Hc1[21], rsh0, rsh1;
    {
      float Rb[9]; mat3mul_u(Rn, Rci_, Rb);
      float vi0 = Rn[0]*vnp[0]+Rn[3]*vnp[1]+Rn[6]*vnp[2];
      float vi1 = Rn[1]*vnp[0]+Rn[4]*vnp[1]+Rn[7]*vnp[2];
      float vi2 = Rn[2]*vnp[0]+Rn[5]*vnp[1]+Rn[8]*vnp[2];
      float o0 = u6[0]-bo_[0], o1 = u6[1]-bo_[1], o2 = u6[2]-bo_[2];
      #pragma unroll
      for (int c=0;c<3;c++){ Hc0[c]=0.f; Hc1[c]=0.f; Hc0[6+c]=0.f; Hc1[6+c]=0.f; Hc0[12+c]=0.f; Hc1[12+c]=0.f; }
      #pragma unroll
      for (int c=0;c<3;c++){ Hc0[3+c]=Rb[c*3+1]; Hc1[3+c]=Rb[c*3+2]; }
      Hc0[9]= tci_[2]; Hc0[10]=0.f;      Hc0[11]=-tci_[0];
      Hc1[9]=-tci_[1]; Hc1[10]=tci_[0];  Hc1[11]=0.f;
      Hc0[15]= Rci_[4]*vi2 - Rci_[7]*vi1;
      Hc0[16]=-Rci_[1]*vi2 + Rci_[7]*vi0;
      Hc0[17]= Rci_[1]*vi1 - Rci_[4]*vi0;
      Hc1[15]= Rci_[5]*vi2 - Rci_[8]*vi1;
      Hc1[16]=-Rci_[2]*vi2 + Rci_[8]*vi0;
      Hc1[17]= Rci_[2]*vi1 - Rci_[5]*vi0;
      Hc0[18]=-o2; Hc0[19]=0.f; Hc0[20]= o0;
      Hc1[18]= o1; Hc1[19]=-o0; Hc1[20]=0.f;
      rsh0 = -( Rci_[1]*vi0 + Rci_[4]*vi1 + Rci_[7]*vi2 + (tci_[2]*o0 - tci_[0]*o2) );
      rsh1 = -( Rci_[2]*vi0 + Rci_[5]*vi1 + Rci_[8]*vi2 + (-tci_[1]*o0 + tci_[0]*o1) );
    }

    // ---- T1 col read + sym avg + GQGT -> areg ----
    float areg[21];
    if (lane<21){
      float colv[21];
      #pragma unroll
      for (int r=0;r<21;r++) colv[r] = TP1[r*24+lane];
      #pragma unroll
      for (int j=0;j<21;j++) areg[j] = 0.5f*(creg[j]+colv[j]);
    } else {
      #pragma unroll
      for (int j=0;j<21;j++) areg[j] = 0.f;
    }
    {
      const float qom = 1e-3f*dt2, qac = 1e-2f*dt2;
      if (lane<9){
        float wi0 = SEL9(R_[0],R_[3],R_[6], vsr[0],vsr[3],vsr[6], psr[0],psr[3],psr[6]);
        float wi1 = SEL9(R_[1],R_[4],R_[7], vsr[1],vsr[4],vsr[7], psr[1],psr[4],psr[7]);
        float wi2 = SEL9(R_[2],R_[5],R_[8], vsr[2],vsr[5],vsr[8], psr[2],psr[5],psr[8]);
        #pragma unroll
        for (int jq=0;jq<9;jq++){
          float wj0 = (jq<3)? R_[jq*3]   : (jq<6)? vsr[(jq-3)*3]   : psr[(jq-6)*3];
          float wj1 = (jq<3)? R_[jq*3+1] : (jq<6)? vsr[(jq-3)*3+1] : psr[(jq-6)*3+1];
          float wj2 = (jq<3)? R_[jq*3+2] : (jq<6)? vsr[(jq-3)*3+2] : psr[(jq-6)*3+2];
          areg[jq] += qom*(wi0*wj0+wi1*wj1+wi2*wj2);
        }
        if (lane>=3 && lane<6){
          float ri0 = (lane==3)?R_[0]:(lane==4)?R_[3]:R_[6];
          float ri1 = (lane==3)?R_[1]:(lane==4)?R_[4]:R_[7];
          float ri2 = (lane==3)?R_[2]:(lane==4)?R_[5]:R_[8];
          areg[3] += qac*(ri0*R_[0]+ri1*R_[1]+ri2*R_[2]);
          areg[4] += qac*(ri0*R_[3]+ri1*R_[4]+ri2*R_[5]);
          areg[5] += qac*(ri0*R_[6]+ri1*R_[7]+ri2*R_[8]);
        }
      }
      float qd = (lane>=9&&lane<12)? 6e-9f : (lane>=12&&lane<15)? 2e-4f : (lane>=15&&lane<21)? 1e-9f : 0.f;
      qd *= dt2;
      #pragma unroll
      for (int j=9;j<21;j++) if (j==lane) areg[j] += qd;
    }

    // ---- U1: B = A + A@N^T (local) ----
    col_update(areg, R_, n13, n23, dtv, hdt2, Gdt, Ghdt2);

    // ---- T2: transpose B ----
    if (lane<21){
      float4* rp = (float4*)&TP2[lane*24];
      rp[0]=make_float4(areg[0],areg[1],areg[2],areg[3]);
      rp[1]=make_float4(areg[4],areg[5],areg[6],areg[7]);
      rp[2]=make_float4(areg[8],areg[9],areg[10],areg[11]);
      rp[3]=make_float4(areg[12],areg[13],areg[14],areg[15]);
      rp[4]=make_float4(areg[16],areg[17],areg[18],areg[19]);
      TP2[lane*24+20]=areg[20];
    }
    float ctreg[21];
    if (lane<21){
      #pragma unroll
      for (int r=0;r<21;r++) ctreg[r] = TP2[r*24+lane];
    } else {
      #pragma unroll
      for (int r=0;r<21;r++) ctreg[r] = 0.f;
    }

    // ---- U2: C^T = B^T + B^T@N^T (local) ----
    col_update(ctreg, R_, n13, n23, dtv, hdt2, Gdt, Ghdt2);

    // ---- PHt per-lane, round-trip through LDS ----
    float ph0=0.f, ph1=0.f;
    #pragma unroll
    for (int j=0;j<21;j++){ ph0 += ctreg[j]*Hc0[j]; ph1 += ctreg[j]*Hc1[j]; }
    if (lane<21){
      *(float2*)&PH[lane*2] = make_float2(ph0, ph1);
    }
    float pj0[21], pj1[21];
    {
      #pragma unroll
      for (int q=0;q<11;q++){
        float4 v4 = ((float4*)PH)[q];
        if (2*q   < 21){ pj0[2*q]   = v4.x; pj1[2*q]   = v4.y; }
        if (2*q+1 < 21){ pj0[2*q+1] = v4.z; pj1[2*q+1] = v4.w; }
      }
    }

    // ---- S, inverse, dx (uniform) ----
    float s00=mc0, s01=0.f, s10=0.f, s11=mc1;
    #pragma unroll
    for (int j=0;j<21;j++){
      s00 += Hc0[j]*pj0[j];
      s01 += Hc0[j]*pj1[j];
      s10 += Hc1[j]*pj0[j];
      s11 += Hc1[j]*pj1[j];
    }
    float id  = 1.f/(s00*s11 - s01*s10);
    float i00 =  s11*id, i01 = -s01*id, i10 = -s10*id, i11 = s00*id;
    float sm01 = 0.5f*(s01+s10);
    float dx[21];
    #pragma unroll
    for (int j=0;j<21;j++){
      float kj0 = pj0[j]*i00 + pj1[j]*i10;
      float kj1 = pj0[j]*i01 + pj1[j]*i11;
      dx[j] = kj0*rsh0 + kj1*rsh1;
    }

    // ---- retraction (uniform) ----
    {
      float q0=dx[0], q1=dx[1], q2=dx[2];
      float a2 = q0*q0+q1*q1+q2*q2;
      float c1,c2,c3; so3coeffs(a2,&c1,&c2,&c3);
      float dR[9], Jm[9];
      dR[0]=1.f+c2*(q0*q0-a2); dR[4]=1.f+c2*(q1*q1-a2); dR[8]=1.f+c2*(q2*q2-a2);
      dR[1]=-c1*q2+c2*q0*q1;   dR[3]= c1*q2+c2*q0*q1;
      dR[2]= c1*q1+c2*q0*q2;   dR[6]=-c1*q1+c2*q0*q2;
      dR[5]=-c1*q0+c2*q1*q2;   dR[7]= c1*q0+c2*q1*q2;
      Jm[0]=1.f+c3*(q0*q0-a2); Jm[4]=1.f+c3*(q1*q1-a2); Jm[8]=1.f+c3*(q2*q2-a2);
      Jm[1]=-c2*q2+c3*q0*q1;   Jm[3]= c2*q2+c3*q0*q1;
      Jm[2]= c2*q1+c3*q0*q2;   Jm[6]=-c2*q1+c3*q0*q2;
      Jm[5]=-c2*q0+c3*q1*q2;   Jm[7]= c2*q0+c3*q1*q2;
      float xv[3], xp[3];
      #pragma unroll
      for (int r=0;r<3;r++){
        xv[r]=Jm[r*3]*dx[3]+Jm[r*3+1]*dx[4]+Jm[r*3+2]*dx[5];
        xp[r]=Jm[r*3]*dx[6]+Jm[r*3+1]*dx[7]+Jm[r*3+2]*dx[8];
      }
      float Rn2[9]; mat3mul_u(dR, Rn, Rn2);
      #pragma unroll
      for (int r=0;r<3;r++){
        float vv = dR[r*3]*vnp[0]+dR[r*3+1]*vnp[1]+dR[r*3+2]*vnp[2] + xv[r];
        float pp = dR[r*3]*pnp[0]+dR[r*3+1]*pnp[1]+dR[r*3+2]*pnp[2] + xp[r];
        v_[r]=vv; p_[r]=pp;
        bo_[r]+=dx[9+r]; ba_[r]+=dx[12+r]; tci_[r]+=dx[18+r];
      }
      float E2[9]; so3exp_u(dx[15],dx[16],dx[17],E2);
      float Rc2[9]; mat3mul_u(E2, Rci_, Rc2);
      #pragma unroll
      for (int k=0;k<9;k++){ Rci_[k]=Rc2[k]; R_[k]=Rn2[k]; }
    }
    // commit state (lane 0)
    if (lane==0){
      ((float4*)stG)[0] = make_float4(R_[0],R_[1],R_[2],R_[3]);
      ((float4*)stG)[1] = make_float4(R_[4],R_[5],R_[6],R_[7]);
      ((float4*)stG)[2] = make_float4(R_[8],v_[0],v_[1],v_[2]);
      ((float4*)stG)[3] = make_float4(p_[0],p_[1],p_[2],bo_[0]);
      ((float4*)stG)[4] = make_float4(bo_[1],bo_[2],ba_[0],ba_[1]);
      ((float4*)stG)[5] = make_float4(ba_[2],Rci_[0],Rci_[1],Rci_[2]);
      ((float4*)stG)[6] = make_float4(Rci_[3],Rci_[4],Rci_[5],Rci_[6]);
      ((float4*)stG)[7] = make_float4(Rci_[7],Rci_[8],tci_[0],tci_[1]);
      ((float4*)stG)[8] = make_float4(tci_[2],0.f,0.f,0.f);
    }

    // ---- rank-2 covariance update (per-lane) ----
    {
      float ki0 = ph0*i00 + ph1*i10;
      float ki1 = ph0*i01 + ph1*i11;
      float ai0 = s00*ki0 + sm01*ki1;
      float ai1 = sm01*ki0 + s11*ki1;
      #pragma unroll
      for (int j=0;j<21;j++){
        float kj0 = pj0[j]*i00 + pj1[j]*i10;
        float kj1 = pj0[j]*i01 + pj1[j]*i11;
        float tsum = (ki0*pj0[j] + ki1*pj1[j]) + (ph0*kj0 + ph1*kj1);
        float quad = ai0*kj0 + ai1*kj1;
        creg[j] = ctreg[j] - tsum + quad;
      }
    }

    // ---- prefetch next inputs (uniform) ----
    {
      int np = n+1;
      t_nm1 = t_n;
      if (np < N){
        t_n = t[np];
        mc0 = mcov[np*2]; mc1 = mcov[np*2+1];
        #pragma unroll
        for (int k=0;k<6;k++) u6[k]=u[np*6+k];
      }
    }
  }

  // final output row
  if (lane<33) out[(size_t)(N-1)*33 + lane] = stG[lane];
}

extern "C" void kernel_launch(void* const* d_in, const int* in_sizes, int n_in,
                              void* d_out, int out_size, void* d_ws, size_t ws_size,
                              hipStream_t stream) {
  const float* t     = (const float*)d_in[0];
  const float* u     = (const float*)d_in[1];
  const float* mcov  = (const float*)d_in[2];
  const float* vmes  = (const float*)d_in[3];
  // d_in[4] = p_mes (unused by reference)
  const float* ang0  = (const float*)d_in[5];
  const float* winit = (const float*)d_in[6];
  float* out = (float*)d_out;
  int N = in_sizes[0];
  iekf_kernel<<<dim3(1), dim3(64), 0, stream>>>(t, u, mcov, vmes, ang0, winit, out, N);
}